// Round 6
// baseline (361.527 us; speedup 1.0000x reference)
//
#include <hip/hip_runtime.h>
#include <hip/hip_bf16.h>
#include <cstdint>
#include <cstddef>

#define BB 8
#define TT 2048
#define CC 2048
#define EE 32
#define HH 64
#define NCH 64   // convsum chunks along T

typedef __bf16 v8bf __attribute__((ext_vector_type(8)));
typedef float v4f __attribute__((ext_vector_type(4)));

// async global->LDS, 16B per lane; LDS dest must be wave-uniform base (+lane*16 by HW)
#define GLOAD16(gp, lp)                                                              \
  __builtin_amdgcn_global_load_lds((const __attribute__((address_space(1))) void*)(gp), \
                                   (__attribute__((address_space(3))) void*)(lp), 16, 0, 0)

// ---------------- kernel 1: token partial sums (read-only pass over hs) ----------------
// grid (B*C/1024, NCH), block 256. float4 loads, 16B/lane.
__global__ void k_convsum(const float* __restrict__ hs, float* __restrict__ partial) {
    int idx4 = blockIdx.x * 256 + threadIdx.x;       // 0 .. B*C/4-1
    int chunk = blockIdx.y;
    int b = idx4 >> 9;                               // C/4 = 512 float4 per b
    int c4 = (idx4 & 511) * 4;
    const int ROWS = TT / NCH;                       // 32 rows per chunk
    const float4* p = (const float4*)(hs + (size_t)b * TT * CC + (size_t)chunk * ROWS * CC + c4);
    float4 s = {0.f, 0.f, 0.f, 0.f};
    #pragma unroll 8
    for (int t = 0; t < ROWS; ++t) {
        float4 v = p[(size_t)t * (CC / 4)];
        s.x += v.x; s.y += v.y; s.z += v.z; s.w += v.w;
    }
    ((float4*)partial)[(size_t)chunk * (BB * CC / 4) + idx4] = s;
}

// ---------------- kernel 1b: collapse NCH chunk partials -> seq_rep (B,C) ----------------
__global__ void k_sumred(const float* __restrict__ partial, float* __restrict__ seqrep) {
    int idx4 = blockIdx.x * 256 + threadIdx.x;       // float4 index
    float4 s = {0.f, 0.f, 0.f, 0.f};
    #pragma unroll 8
    for (int ch = 0; ch < NCH; ++ch) {
        float4 v = ((const float4*)partial)[(size_t)ch * (BB * CC / 4) + idx4];
        s.x += v.x; s.y += v.y; s.z += v.z; s.w += v.w;
    }
    ((float4*)seqrep)[idx4] = s;
}

// ---------------- kernel 2: affinity logits, one block per (e,b) ----------------
// note: 1/T mean factor cancels in the cosine normalization -> skipped
__global__ void k_affinity(const float* __restrict__ seqrep, const float* __restrict__ sim,
                           const float* __restrict__ gates, float* __restrict__ logits) {
    __shared__ float red[256];
    int e = blockIdx.x, b = blockIdx.y, tid = threadIdx.x;
    float d = 0.f, n = 0.f, m2 = 0.f;
    for (int c = tid; c < CC; c += 256) {
        float sr = seqrep[b * CC + c];
        float sv = sim[(size_t)c * EE + e];
        d += sr * sv; n += sv * sv; m2 += sr * sr;
    }
    red[tid] = d; __syncthreads();
    for (int s = 128; s > 0; s >>= 1) { if (tid < s) red[tid] += red[tid + s]; __syncthreads(); }
    d = red[0]; __syncthreads();
    red[tid] = n; __syncthreads();
    for (int s = 128; s > 0; s >>= 1) { if (tid < s) red[tid] += red[tid + s]; __syncthreads(); }
    n = red[0]; __syncthreads();
    red[tid] = m2; __syncthreads();
    for (int s = 128; s > 0; s >>= 1) { if (tid < s) red[tid] += red[tid + s]; __syncthreads(); }
    m2 = red[0];
    if (tid == 0) {
        float aff = d * rsqrtf(n) * rsqrtf(m2);
        float sg = 1.0f / (1.0f + expf(-gates[e]));
        logits[b * EE + e] = aff - sg;
    }
}

// ---------------- kernel 3: routing + weight mix fused ----------------
// grid (H*C/1024, 2), block 256. y==0 -> wv_eff [b][h][c]; y==1 -> wo_t TRANSPOSED [b][d][h]
// (transposed so the fused GEMM's phase-2 B-fragments are direct 16B global loads).
// Routing computed wave-parallel: thread tid = b*32+e.
__global__ void k_wmix(const float* __restrict__ w_v, const float* __restrict__ o_w,
                       const float* __restrict__ logits,
                       __hip_bfloat16* __restrict__ wv_eff, __hip_bfloat16* __restrict__ wo_t) {
    __shared__ float r[BB * EE];
    int tid = threadIdx.x;
    int lane = tid & 63;
    int sub = lane & 31;                 // e within 32-lane expert group
    float lg = logits[tid];              // BB*EE == 256 == blockDim
    float gated = lg > 0.f ? lg : 0.f;
    bool act = gated > 0.f;
    unsigned long long bal = __ballot(act);
    unsigned halfmask = (lane & 32) ? (unsigned)(bal >> 32) : (unsigned)bal;
    bool sel;
    if (__popc(halfmask) == 0) {
        // fallback: top-(E/2) by raw logits within this sequence's 32-lane group
        int base = lane & 32;
        int rank = 0;
        #pragma unroll
        for (int j = 0; j < EE; ++j) {
            float lj = __shfl(lg, base + j, 64);
            rank += (lj > lg) || (lj == lg && j < sub);
        }
        sel = rank < (EE / 2);
    } else {
        sel = act;
    }
    float mv = sel ? gated : -3.402823466e+38f;
    #pragma unroll
    for (int k = 16; k >= 1; k >>= 1) mv = fmaxf(mv, __shfl_xor(mv, k, 64));
    float ex = sel ? expf(gated - mv) : 0.f;
    float ss = ex;
    #pragma unroll
    for (int k = 16; k >= 1; k >>= 1) ss += __shfl_xor(ss, k, 64);
    r[tid] = ex / ss;
    __syncthreads();

    size_t idx4 = (size_t)blockIdx.x * 256 + tid;     // float4 index into (H*C)
    const float4* w = (const float4*)(blockIdx.y ? o_w : w_v);
    float4 acc[BB] = {};
    for (int e = 0; e < EE; ++e) {
        float4 v = w[(size_t)e * (HH * CC / 4) + idx4];
        #pragma unroll
        for (int b = 0; b < BB; ++b) {
            float rv = r[b * EE + e];
            acc[b].x += rv * v.x; acc[b].y += rv * v.y;
            acc[b].z += rv * v.z; acc[b].w += rv * v.w;
        }
    }
    if (blockIdx.y == 0) {
        #pragma unroll
        for (int b = 0; b < BB; ++b) {
            union { __hip_bfloat16 h[4]; ushort4 u; } o;
            o.h[0] = __float2bfloat16(acc[b].x); o.h[1] = __float2bfloat16(acc[b].y);
            o.h[2] = __float2bfloat16(acc[b].z); o.h[3] = __float2bfloat16(acc[b].w);
            *(ushort4*)&wv_eff[(size_t)b * HH * CC + idx4 * 4] = o.u;
        }
    } else {
        // transposed scatter: source element (h, d) -> wo_t[b][d][h]
        int h = (int)(idx4 >> 9);                  // (idx4*4) / CC
        int dbase = (int)((idx4 & 511) * 4);       // (idx4*4) % CC
        #pragma unroll
        for (int b = 0; b < BB; ++b) {
            float vals[4] = {acc[b].x, acc[b].y, acc[b].z, acc[b].w};
            #pragma unroll
            for (int k = 0; k < 4; ++k)
                wo_t[((size_t)b * CC + dbase + k) * HH + h] = __float2bfloat16(vals[k]);
        }
    }
}

// ---------------- kernel 4: FUSED GEMM: out = (cvt(hs) @ wve^T) @ wo_t ----------------
// grid (T/64, B) = 256 blocks (1/CU), block 1024 (16 waves, 4/SIMD).
// Phase 1: 4 groups x 256 threads, split-K=4 over C; each group = verified k_gemm1
//   structure (XOR-swizzled LDS, global_load_lds B, reg-cvt A). Partials -> LDS psum
//   (aliases staging, 64 KB), in-LDS reduce -> bf16 comb tile cl[64][72].
// Phase 2: 16 waves, wave w -> rows (w&3)*16, cols (w>>2)*512 in 8 tiles of 64.
//   A-fragments hoisted from cl; B-fragments 16B direct global loads from wo_t[b][d][h]
//   (L2-resident). No phase-2 barriers. Eliminates partialC/comb HBM round-trips.
__global__ __launch_bounds__(1024) void k_gemmf(const float* __restrict__ A,
                                                const __hip_bfloat16* __restrict__ Bw,
                                                const __hip_bfloat16* __restrict__ Wt,
                                                float* __restrict__ out) {
    __shared__ __align__(16) char smem[65536];
    int tid = threadIdx.x;
    int t0 = blockIdx.x * 64;
    int b  = blockIdx.y;
    int g  = tid >> 8;                 // K-slice group 0..3
    int tg = tid & 255;
    int lane = tid & 63, lm = lane & 15, quad = lane >> 4;
    int wg = (tid >> 6) & 3;           // wave within group

    char* Abase = smem + g * 8192;             // group A tile: 64x64 bf16
    char* Bbase = smem + 32768 + g * 8192;     // group B tile: 64x64 bf16

    // B staging (async): 2 chunks per thread, XOR-swizzled global source
    const __hip_bfloat16* Bg = Bw + (size_t)b * HH * CC;
    int L0 = tg, L1 = tg + 256;
    int row0 = L0 >> 3, c0 = ((L0 & 7) ^ (row0 & 7)) * 8;
    int row1 = L1 >> 3, c1 = ((L1 & 7) ^ (row1 & 7)) * 8;
    int ldsoff0 = tg * 16, ldsoff1 = (tg + 256) * 16;
    // A reg-stage mapping: thread -> (row ar, 16-float group aq)
    int ar = tg >> 2, aq = tg & 3;
    const float* Ag = A + ((size_t)b * TT + t0 + ar) * CC + aq * 16;
    int as0 = (ar * 8 + ((2 * aq) ^ (ar & 7))) * 16;
    int as1 = (ar * 8 + ((2 * aq + 1) ^ (ar & 7))) * 16;

    v4f acc[4] = {};
    int k0 = g * (CC / 4);
    for (int it = 0; it < 8; ++it) {           // uniform trip count across groups
        int kk0 = k0 + it * 64;
        GLOAD16(Bg + (size_t)row0 * CC + kk0 + c0, Bbase + ldsoff0);
        GLOAD16(Bg + (size_t)row1 * CC + kk0 + c1, Bbase + ldsoff1);
        float4 f0 = *(const float4*)(Ag + kk0);
        float4 f1 = *(const float4*)(Ag + kk0 + 4);
        float4 f2 = *(const float4*)(Ag + kk0 + 8);
        float4 f3 = *(const float4*)(Ag + kk0 + 12);
        union { v8bf v; __hip_bfloat16 h[8]; } u0, u1;
        u0.h[0] = __float2bfloat16(f0.x); u0.h[1] = __float2bfloat16(f0.y);
        u0.h[2] = __float2bfloat16(f0.z); u0.h[3] = __float2bfloat16(f0.w);
        u0.h[4] = __float2bfloat16(f1.x); u0.h[5] = __float2bfloat16(f1.y);
        u0.h[6] = __float2bfloat16(f1.z); u0.h[7] = __float2bfloat16(f1.w);
        u1.h[0] = __float2bfloat16(f2.x); u1.h[1] = __float2bfloat16(f2.y);
        u1.h[2] = __float2bfloat16(f2.z); u1.h[3] = __float2bfloat16(f2.w);
        u1.h[4] = __float2bfloat16(f3.x); u1.h[5] = __float2bfloat16(f3.y);
        u1.h[6] = __float2bfloat16(f3.z); u1.h[7] = __float2bfloat16(f3.w);
        *(v8bf*)(Abase + as0) = u0.v;
        *(v8bf*)(Abase + as1) = u1.v;
        __syncthreads();
        int arow = wg * 16 + lm;
        #pragma unroll
        for (int s = 0; s < 2; ++s) {
            v8bf a = *(const v8bf*)(Abase + (arow * 8 + ((s * 4 + quad) ^ (arow & 7))) * 16);
            #pragma unroll
            for (int j = 0; j < 4; ++j) {
                int brow = j * 16 + lm;
                v8bf bb = *(const v8bf*)(Bbase + (brow * 8 + ((s * 4 + quad) ^ (brow & 7))) * 16);
                acc[j] = __builtin_amdgcn_mfma_f32_16x16x32_bf16(a, bb, acc[j], 0, 0, 0);
            }
        }
        __syncthreads();
    }

    // psum: [4 g][64 r][64 c] f32 = 64 KB, aliases staging (all staging reads done)
    float* ps = (float*)smem;
    #pragma unroll
    for (int j = 0; j < 4; ++j)
        #pragma unroll
        for (int r2 = 0; r2 < 4; ++r2)
            ps[(g * 64 + wg * 16 + quad * 4 + r2) * 64 + j * 16 + lm] = acc[j][r2];
    __syncthreads();

    // reduce 4 K-slices -> regs, then overwrite front of smem with bf16 comb tile
    int rr = tid >> 4, cc4 = (tid & 15) * 4;
    const float4* pp = (const float4*)smem;
    int pidx = rr * 16 + (cc4 >> 2);
    float4 s0 = pp[pidx], s1 = pp[1024 + pidx], s2 = pp[2048 + pidx], s3 = pp[3072 + pidx];
    union { __hip_bfloat16 h[4]; ushort4 u; } cu;
    cu.h[0] = __float2bfloat16(s0.x + s1.x + s2.x + s3.x);
    cu.h[1] = __float2bfloat16(s0.y + s1.y + s2.y + s3.y);
    cu.h[2] = __float2bfloat16(s0.z + s1.z + s2.z + s3.z);
    cu.h[3] = __float2bfloat16(s0.w + s1.w + s2.w + s3.w);
    __syncthreads();
    __hip_bfloat16* cl = (__hip_bfloat16*)smem;     // 64 x 72 bf16 comb tile
    *(ushort4*)&cl[rr * 72 + cc4] = cu.u;
    __syncthreads();

    // phase 2: out tile 64 x 2048 = comb(64x64) @ wo_t
    int w = tid >> 6;                  // 0..15
    int r4 = w & 3, cg = w >> 2;
    v8bf a0 = *(const v8bf*)&cl[(r4 * 16 + lm) * 72 + quad * 8];
    v8bf a1 = *(const v8bf*)&cl[(r4 * 16 + lm) * 72 + 32 + quad * 8];
    const __hip_bfloat16* Wb = Wt + (size_t)b * CC * HH;
    float* Og = out + (size_t)b * TT * CC + (size_t)t0 * CC;
    for (int it = 0; it < 8; ++it) {
        int d0 = cg * 512 + it * 64;
        #pragma unroll
        for (int j = 0; j < 4; ++j) {
            int brow = d0 + j * 16 + lm;
            v8bf b0 = *(const v8bf*)&Wb[(size_t)brow * HH + quad * 8];
            v8bf b1 = *(const v8bf*)&Wb[(size_t)brow * HH + 32 + quad * 8];
            v4f a2 = {};
            a2 = __builtin_amdgcn_mfma_f32_16x16x32_bf16(a0, b0, a2, 0, 0, 0);
            a2 = __builtin_amdgcn_mfma_f32_16x16x32_bf16(a1, b1, a2, 0, 0, 0);
            #pragma unroll
            for (int r2 = 0; r2 < 4; ++r2)
                Og[(size_t)(r4 * 16 + quad * 4 + r2) * CC + d0 + j * 16 + lm] = a2[r2];
        }
    }
}

extern "C" void kernel_launch(void* const* d_in, const int* in_sizes, int n_in,
                              void* d_out, int out_size, void* d_ws, size_t ws_size,
                              hipStream_t stream) {
    const float* hs    = (const float*)d_in[0];   // (B,T,C)
    const float* sim   = (const float*)d_in[1];   // (C,E)
    const float* gates = (const float*)d_in[2];   // (E,)
    // d_in[3]=w_q, d_in[4]=w_k: dead (seq_len-1 SDPA == identity on v)
    const float* w_v   = (const float*)d_in[5];   // (E,H,C)
    const float* o_w   = (const float*)d_in[6];   // (E,H,C)
    float* out = (float*)d_out;
    float* ws  = (float*)d_ws;

    // workspace layout (float units)
    size_t o = 0;
    float* partial = ws + o;                          o += (size_t)NCH * BB * CC;    // 4 MB
    float* seqrep  = ws + o;                          o += BB * CC;
    float* logits  = ws + o;                          o += BB * EE;
    __hip_bfloat16* wve = (__hip_bfloat16*)(ws + o);  o += (size_t)BB * HH * CC / 2; // 2 MB
    __hip_bfloat16* wot = (__hip_bfloat16*)(ws + o);  o += (size_t)BB * HH * CC / 2; // 2 MB

    hipLaunchKernelGGL(k_convsum, dim3(BB * CC / 1024, NCH), dim3(256), 0, stream,
                       hs, partial);
    hipLaunchKernelGGL(k_sumred, dim3(BB * CC / 1024), dim3(256), 0, stream,
                       partial, seqrep);
    hipLaunchKernelGGL(k_affinity, dim3(EE, BB), dim3(256), 0, stream,
                       seqrep, sim, gates, logits);
    hipLaunchKernelGGL(k_wmix, dim3(HH * CC / 1024, 2), dim3(256), 0, stream,
                       w_v, o_w, logits, wve, wot);
    hipLaunchKernelGGL(k_gemmf, dim3(TT / 64, BB), dim3(1024), 0, stream,
                       hs, wve, wot, out);
}

// Round 7
// 341.757 us; speedup vs baseline: 1.0578x; 1.0578x over previous
//
#include <hip/hip_runtime.h>
#include <hip/hip_bf16.h>
#include <cstdint>
#include <cstddef>

#define BB 8
#define TT 2048
#define CC 2048
#define EE 32
#define HH 64
#define NCH 64   // convsum chunks along T

typedef __bf16 v8bf __attribute__((ext_vector_type(8)));
typedef float v4f __attribute__((ext_vector_type(4)));

// async global->LDS, 16B per lane; LDS dest must be wave-uniform base (+lane*16 by HW)
#define GLOAD16(gp, lp)                                                              \
  __builtin_amdgcn_global_load_lds((const __attribute__((address_space(1))) void*)(gp), \
                                   (__attribute__((address_space(3))) void*)(lp), 16, 0, 0)

// ---------------- kernel 1: token partial sums (read-only pass over hs) ----------------
// grid (B*C/1024, NCH), block 256. float4 loads, 16B/lane.
__global__ void k_convsum(const float* __restrict__ hs, float* __restrict__ partial) {
    int idx4 = blockIdx.x * 256 + threadIdx.x;       // 0 .. B*C/4-1
    int chunk = blockIdx.y;
    int b = idx4 >> 9;                               // C/4 = 512 float4 per b
    int c4 = (idx4 & 511) * 4;
    const int ROWS = TT / NCH;                       // 32 rows per chunk
    const float4* p = (const float4*)(hs + (size_t)b * TT * CC + (size_t)chunk * ROWS * CC + c4);
    float4 s = {0.f, 0.f, 0.f, 0.f};
    #pragma unroll 8
    for (int t = 0; t < ROWS; ++t) {
        float4 v = p[(size_t)t * (CC / 4)];
        s.x += v.x; s.y += v.y; s.z += v.z; s.w += v.w;
    }
    ((float4*)partial)[(size_t)chunk * (BB * CC / 4) + idx4] = s;
}

// ---------------- kernel 1b: collapse NCH chunk partials -> seq_rep (B,C) ----------------
__global__ void k_sumred(const float* __restrict__ partial, float* __restrict__ seqrep) {
    int idx4 = blockIdx.x * 256 + threadIdx.x;       // float4 index
    float4 s = {0.f, 0.f, 0.f, 0.f};
    #pragma unroll 8
    for (int ch = 0; ch < NCH; ++ch) {
        float4 v = ((const float4*)partial)[(size_t)ch * (BB * CC / 4) + idx4];
        s.x += v.x; s.y += v.y; s.z += v.z; s.w += v.w;
    }
    ((float4*)seqrep)[idx4] = s;
}

// ---------------- kernel 2: affinity logits, one block per (e,b) ----------------
// note: 1/T mean factor cancels in the cosine normalization -> skipped
__global__ void k_affinity(const float* __restrict__ seqrep, const float* __restrict__ sim,
                           const float* __restrict__ gates, float* __restrict__ logits) {
    __shared__ float red[256];
    int e = blockIdx.x, b = blockIdx.y, tid = threadIdx.x;
    float d = 0.f, n = 0.f, m2 = 0.f;
    for (int c = tid; c < CC; c += 256) {
        float sr = seqrep[b * CC + c];
        float sv = sim[(size_t)c * EE + e];
        d += sr * sv; n += sv * sv; m2 += sr * sr;
    }
    red[tid] = d; __syncthreads();
    for (int s = 128; s > 0; s >>= 1) { if (tid < s) red[tid] += red[tid + s]; __syncthreads(); }
    d = red[0]; __syncthreads();
    red[tid] = n; __syncthreads();
    for (int s = 128; s > 0; s >>= 1) { if (tid < s) red[tid] += red[tid + s]; __syncthreads(); }
    n = red[0]; __syncthreads();
    red[tid] = m2; __syncthreads();
    for (int s = 128; s > 0; s >>= 1) { if (tid < s) red[tid] += red[tid + s]; __syncthreads(); }
    m2 = red[0];
    if (tid == 0) {
        float aff = d * rsqrtf(n) * rsqrtf(m2);
        float sg = 1.0f / (1.0f + expf(-gates[e]));
        logits[b * EE + e] = aff - sg;
    }
}

// ---------------- kernel 3: routing + weight mix fused ----------------
// grid (H*C/1024, 2), block 256. y==0 -> wv_eff, y==1 -> wo_eff (both [b][h][c]).
// Routing computed wave-parallel: thread tid = b*32+e.
// Weight stream vectorized: float4 loads (16B/lane), ushort4 bf16 stores (8B/lane).
__global__ void k_wmix(const float* __restrict__ w_v, const float* __restrict__ o_w,
                       const float* __restrict__ logits,
                       __hip_bfloat16* __restrict__ wv_eff, __hip_bfloat16* __restrict__ wo_eff) {
    __shared__ float r[BB * EE];
    int tid = threadIdx.x;
    int lane = tid & 63;
    int sub = lane & 31;                 // e within 32-lane expert group
    float lg = logits[tid];              // BB*EE == 256 == blockDim
    float gated = lg > 0.f ? lg : 0.f;
    bool act = gated > 0.f;
    unsigned long long bal = __ballot(act);
    unsigned halfmask = (lane & 32) ? (unsigned)(bal >> 32) : (unsigned)bal;
    bool sel;
    if (__popc(halfmask) == 0) {
        // fallback: top-(E/2) by raw logits within this sequence's 32-lane group
        int base = lane & 32;
        int rank = 0;
        #pragma unroll
        for (int j = 0; j < EE; ++j) {
            float lj = __shfl(lg, base + j, 64);
            rank += (lj > lg) || (lj == lg && j < sub);
        }
        sel = rank < (EE / 2);
    } else {
        sel = act;
    }
    float mv = sel ? gated : -3.402823466e+38f;
    #pragma unroll
    for (int k = 16; k >= 1; k >>= 1) mv = fmaxf(mv, __shfl_xor(mv, k, 64));
    float ex = sel ? expf(gated - mv) : 0.f;
    float ss = ex;
    #pragma unroll
    for (int k = 16; k >= 1; k >>= 1) ss += __shfl_xor(ss, k, 64);
    r[tid] = ex / ss;
    __syncthreads();

    size_t idx4 = (size_t)blockIdx.x * 256 + tid;     // float4 index into (H*C)
    const float4* w = (const float4*)(blockIdx.y ? o_w : w_v);
    __hip_bfloat16* dst = blockIdx.y ? wo_eff : wv_eff;
    float4 acc[BB] = {};
    for (int e = 0; e < EE; ++e) {
        float4 v = w[(size_t)e * (HH * CC / 4) + idx4];
        #pragma unroll
        for (int b = 0; b < BB; ++b) {
            float rv = r[b * EE + e];
            acc[b].x += rv * v.x; acc[b].y += rv * v.y;
            acc[b].z += rv * v.z; acc[b].w += rv * v.w;
        }
    }
    #pragma unroll
    for (int b = 0; b < BB; ++b) {
        union { __hip_bfloat16 h[4]; ushort4 u; } o;
        o.h[0] = __float2bfloat16(acc[b].x); o.h[1] = __float2bfloat16(acc[b].y);
        o.h[2] = __float2bfloat16(acc[b].z); o.h[3] = __float2bfloat16(acc[b].w);
        *(ushort4*)&dst[(size_t)b * HH * CC + idx4 * 4] = o.u;
    }
}

// ---------------- kernel 4: GEMM1 fused with split-K reduce -> comb bf16 ----------------
// grid (T/64, B) = 256 blocks, block 1024 = 4 groups x 256 threads (16 waves, 4/SIMD —
// same waves/SIMD as the verified 4-block split-K layout). Each group g computes the
// K-slice [g*512, (g+1)*512) of the 64x64 comb tile with the verified k_gemm1 inner
// structure (XOR-swizzled LDS, global_load_lds B, reg-cvt fp32 A). Partials -> LDS psum
// (64 KB, aliases staging after last barrier), in-LDS reduce -> coalesced bf16 comb
// write. Eliminates the partialC 16.8 MB write + read and the k_reduce launch.
// Phase-1 structure is exactly round-6's (passed correctness end-to-end).
__global__ __launch_bounds__(1024) void k_gemm1f(const float* __restrict__ A,
                                                 const __hip_bfloat16* __restrict__ Bw,
                                                 __hip_bfloat16* __restrict__ comb) {
    __shared__ __align__(16) char smem[65536];
    int tid = threadIdx.x;
    int t0 = blockIdx.x * 64;
    int b  = blockIdx.y;
    int g  = tid >> 8;                 // K-slice group 0..3
    int tg = tid & 255;
    int lane = tid & 63, lm = lane & 15, quad = lane >> 4;
    int wg = (tid >> 6) & 3;           // wave within group

    char* Abase = smem + g * 8192;             // group A tile: 64x64 bf16
    char* Bbase = smem + 32768 + g * 8192;     // group B tile: 64x64 bf16

    // B staging (async): 2 chunks per thread, XOR-swizzled global source
    const __hip_bfloat16* Bg = Bw + (size_t)b * HH * CC;
    int L0 = tg, L1 = tg + 256;
    int row0 = L0 >> 3, c0 = ((L0 & 7) ^ (row0 & 7)) * 8;
    int row1 = L1 >> 3, c1 = ((L1 & 7) ^ (row1 & 7)) * 8;
    int ldsoff0 = tg * 16, ldsoff1 = (tg + 256) * 16;
    // A reg-stage mapping: thread -> (row ar, 16-float group aq)
    int ar = tg >> 2, aq = tg & 3;
    const float* Ag = A + ((size_t)b * TT + t0 + ar) * CC + aq * 16;
    int as0 = (ar * 8 + ((2 * aq) ^ (ar & 7))) * 16;
    int as1 = (ar * 8 + ((2 * aq + 1) ^ (ar & 7))) * 16;

    v4f acc[4] = {};
    int k0 = g * (CC / 4);
    for (int it = 0; it < 8; ++it) {           // uniform trip count across groups
        int kk0 = k0 + it * 64;
        GLOAD16(Bg + (size_t)row0 * CC + kk0 + c0, Bbase + ldsoff0);
        GLOAD16(Bg + (size_t)row1 * CC + kk0 + c1, Bbase + ldsoff1);
        float4 f0 = *(const float4*)(Ag + kk0);
        float4 f1 = *(const float4*)(Ag + kk0 + 4);
        float4 f2 = *(const float4*)(Ag + kk0 + 8);
        float4 f3 = *(const float4*)(Ag + kk0 + 12);
        union { v8bf v; __hip_bfloat16 h[8]; } u0, u1;
        u0.h[0] = __float2bfloat16(f0.x); u0.h[1] = __float2bfloat16(f0.y);
        u0.h[2] = __float2bfloat16(f0.z); u0.h[3] = __float2bfloat16(f0.w);
        u0.h[4] = __float2bfloat16(f1.x); u0.h[5] = __float2bfloat16(f1.y);
        u0.h[6] = __float2bfloat16(f1.z); u0.h[7] = __float2bfloat16(f1.w);
        u1.h[0] = __float2bfloat16(f2.x); u1.h[1] = __float2bfloat16(f2.y);
        u1.h[2] = __float2bfloat16(f2.z); u1.h[3] = __float2bfloat16(f2.w);
        u1.h[4] = __float2bfloat16(f3.x); u1.h[5] = __float2bfloat16(f3.y);
        u1.h[6] = __float2bfloat16(f3.z); u1.h[7] = __float2bfloat16(f3.w);
        *(v8bf*)(Abase + as0) = u0.v;
        *(v8bf*)(Abase + as1) = u1.v;
        __syncthreads();
        int arow = wg * 16 + lm;
        #pragma unroll
        for (int s = 0; s < 2; ++s) {
            v8bf a = *(const v8bf*)(Abase + (arow * 8 + ((s * 4 + quad) ^ (arow & 7))) * 16);
            #pragma unroll
            for (int j = 0; j < 4; ++j) {
                int brow = j * 16 + lm;
                v8bf bb = *(const v8bf*)(Bbase + (brow * 8 + ((s * 4 + quad) ^ (brow & 7))) * 16);
                acc[j] = __builtin_amdgcn_mfma_f32_16x16x32_bf16(a, bb, acc[j], 0, 0, 0);
            }
        }
        __syncthreads();
    }

    // psum: [4 g][64 r][64 c] f32 = 64 KB, aliases staging (all staging reads done)
    float* ps = (float*)smem;
    #pragma unroll
    for (int j = 0; j < 4; ++j)
        #pragma unroll
        for (int r2 = 0; r2 < 4; ++r2)
            ps[(g * 64 + wg * 16 + quad * 4 + r2) * 64 + j * 16 + lm] = acc[j][r2];
    __syncthreads();

    // reduce 4 K-slices -> bf16 comb, coalesced ushort4 stores (8B/lane)
    int rr = tid >> 4, cc4 = (tid & 15) * 4;
    const float4* pp = (const float4*)smem;
    int pidx = rr * 16 + (cc4 >> 2);
    float4 s0 = pp[pidx], s1 = pp[1024 + pidx], s2 = pp[2048 + pidx], s3 = pp[3072 + pidx];
    union { __hip_bfloat16 h[4]; ushort4 u; } cu;
    cu.h[0] = __float2bfloat16(s0.x + s1.x + s2.x + s3.x);
    cu.h[1] = __float2bfloat16(s0.y + s1.y + s2.y + s3.y);
    cu.h[2] = __float2bfloat16(s0.z + s1.z + s2.z + s3.z);
    cu.h[3] = __float2bfloat16(s0.w + s1.w + s2.w + s3.w);
    *(ushort4*)&comb[((size_t)b * TT + t0 + rr) * HH + cc4] = cu.u;
}

// ---------------- kernel 5: GEMM2 bf16 MFMA: out = combined @ w_o_dyn ----------------
// grid (C/64, T/64, B), block 256. K=64 single-shot; B staged transposed with pad 72.
// B staging: v8bf global loads (16B/lane, 2 iters) + scalar LDS transpose-scatter.
// C epilogue: acc -> LDS f32 tile (stride 68) -> float4 coalesced stores (1KB/wave).
// smem = max(2*9216 staging, 64*68*4 epilogue) = 18432 B.  (verified in round 5)
__global__ __launch_bounds__(256) void k_gemm2(const __hip_bfloat16* __restrict__ comb,
                                               const __hip_bfloat16* __restrict__ Wo,
                                               float* __restrict__ out) {
    __shared__ __align__(16) char smem[18432];
    __hip_bfloat16* As = (__hip_bfloat16*)smem;              // 64*72 bf16 = 9216 B
    __hip_bfloat16* Bs = (__hip_bfloat16*)(smem + 9216);     // 64*72 bf16 = 9216 B
    int tid = threadIdx.x;
    int d0 = blockIdx.x * 64, t0 = blockIdx.y * 64, b = blockIdx.z;
    const __hip_bfloat16* Ag = comb + (size_t)b * TT * HH + (size_t)t0 * HH;
    const __hip_bfloat16* Bg = Wo + (size_t)b * HH * CC + d0;
    #pragma unroll
    for (int r = 0; r < 2; ++r) {              // A tile: [t][h] rows contiguous
        int L = tid + r * 256;
        int row = L >> 3, c = (L & 7) * 8;
        *(int4*)&As[row * 72 + c] = *(const int4*)&Ag[row * 64 + c];
    }
    #pragma unroll
    for (int i = 0; i < 2; ++i) {              // B tile transposed: Bs[d][h] = Wo[h][d0+d]
        int e2 = tid + i * 256;                // (h, d-group of 8)
        int h = e2 >> 3, dg = (e2 & 7) * 8;
        union { v8bf v; __hip_bfloat16 hh[8]; } u;
        u.v = *(const v8bf*)&Bg[(size_t)h * CC + dg];
        #pragma unroll
        for (int j = 0; j < 8; ++j) Bs[(dg + j) * 72 + h] = u.hh[j];
    }
    __syncthreads();
    int wv = tid >> 6, lane = tid & 63, lm = lane & 15, quad = lane >> 4;
    v4f acc[4] = {};
    #pragma unroll
    for (int s = 0; s < 2; ++s) {
        v8bf a = *(const v8bf*)&As[(wv * 16 + lm) * 72 + s * 32 + quad * 8];
        #pragma unroll
        for (int j = 0; j < 4; ++j) {
            v8bf bb = *(const v8bf*)&Bs[(j * 16 + lm) * 72 + s * 32 + quad * 8];
            acc[j] = __builtin_amdgcn_mfma_f32_16x16x32_bf16(a, bb, acc[j], 0, 0, 0);
        }
    }
    __syncthreads();                           // all MFMA LDS reads done; reuse smem
    float* Cl = (float*)smem;                  // 64 x 68 f32 tile = 17408 B
    #pragma unroll
    for (int j = 0; j < 4; ++j)
        #pragma unroll
        for (int r2 = 0; r2 < 4; ++r2)
            Cl[(wv * 16 + quad * 4 + r2) * 68 + j * 16 + lm] = acc[j][r2];
    __syncthreads();
    float* Og = out + (size_t)b * TT * CC + (size_t)t0 * CC + d0;
    #pragma unroll
    for (int p = 0; p < 4; ++p) {              // 16 rows x 16 float4 per pass
        int lin = tid + p * 256;
        int row = lin >> 4, c4 = (lin & 15) * 4;
        *(float4*)&Og[(size_t)row * CC + c4] = *(const float4*)&Cl[row * 68 + c4];
    }
}

extern "C" void kernel_launch(void* const* d_in, const int* in_sizes, int n_in,
                              void* d_out, int out_size, void* d_ws, size_t ws_size,
                              hipStream_t stream) {
    const float* hs    = (const float*)d_in[0];   // (B,T,C)
    const float* sim   = (const float*)d_in[1];   // (C,E)
    const float* gates = (const float*)d_in[2];   // (E,)
    // d_in[3]=w_q, d_in[4]=w_k: dead (seq_len-1 SDPA == identity on v)
    const float* w_v   = (const float*)d_in[5];   // (E,H,C)
    const float* o_w   = (const float*)d_in[6];   // (E,H,C)
    float* out = (float*)d_out;
    float* ws  = (float*)d_ws;

    // workspace layout (float units)
    size_t o = 0;
    float* partial = ws + o;                          o += (size_t)NCH * BB * CC;    // 4 MB
    float* seqrep  = ws + o;                          o += BB * CC;
    float* logits  = ws + o;                          o += BB * EE;
    __hip_bfloat16* comb = (__hip_bfloat16*)(ws + o); o += (size_t)BB * TT * HH / 2; // 2 MB
    __hip_bfloat16* wve  = (__hip_bfloat16*)(ws + o); o += (size_t)BB * HH * CC / 2; // 2 MB
    __hip_bfloat16* woe  = (__hip_bfloat16*)(ws + o); o += (size_t)BB * HH * CC / 2; // 2 MB

    hipLaunchKernelGGL(k_convsum, dim3(BB * CC / 1024, NCH), dim3(256), 0, stream,
                       hs, partial);
    hipLaunchKernelGGL(k_sumred, dim3(BB * CC / 1024), dim3(256), 0, stream,
                       partial, seqrep);
    hipLaunchKernelGGL(k_affinity, dim3(EE, BB), dim3(256), 0, stream,
                       seqrep, sim, gates, logits);
    hipLaunchKernelGGL(k_wmix, dim3(HH * CC / 1024, 2), dim3(256), 0, stream,
                       w_v, o_w, logits, wve, woe);
    hipLaunchKernelGGL(k_gemm1f, dim3(TT / 64, BB), dim3(1024), 0, stream,
                       hs, wve, comb);
    hipLaunchKernelGGL(k_gemm2, dim3(CC / 64, TT / 64, BB), dim3(256), 0, stream,
                       comb, woe, out);
}